// Round 7
// baseline (133.408 us; speedup 1.0000x reference)
//
#include <hip/hip_runtime.h>

#define NPATH 60
#define KDIM  204
#define NIJ   324
#define NTIL  21       // 21 n-tiles of 16 (324 -> 336)
#define HID   64

typedef short bf16x8 __attribute__((ext_vector_type(8)));
typedef float f32x4  __attribute__((ext_vector_type(4)));

// One-time prepped operands in bf16 MFMA B-fragment order (module globals:
// graph-safe, rewritten by prep_kernel every call).
__device__ __align__(16) unsigned short g_w1s[4096];    // 2kc x 4nt x 64lane x 8
__device__ __align__(16) unsigned short g_w2s[4096];
__device__ __align__(16) unsigned short g_cgs[75264];   // 7kc x 21nt x 64lane x 8
__device__ unsigned int  g_pyk[112];                    // per k-pair: p0|y0<<8|p1<<16|y1<<24

// Proven RNE f32->bf16 (round-0 verified). Do NOT replace with
// v_cvt_pk_bf16_f32 asm: round-1 showed that path zeroes the pipeline.
__device__ inline unsigned short f2bf(float f) {
    unsigned int u = __builtin_bit_cast(unsigned int, f);
    u += 0x7fffu + ((u >> 16) & 1u);     // RNE
    return (unsigned short)(u >> 16);
}
__device__ inline float bf2f(unsigned short h) {
    unsigned int u = ((unsigned int)h) << 16;
    return __builtin_bit_cast(float, u);
}

__global__ void prep_kernel(const float* __restrict__ W1, const float* __restrict__ W2,
                            const float* __restrict__ cg, const float* __restrict__ rf,
                            const float* __restrict__ ylm)
{
    int idx = blockIdx.x * 256 + threadIdx.x;
    if (idx < 4096) {                                       // W1 -> fragment order
        int e = idx & 7, ln = (idx >> 3) & 63, nt = (idx >> 9) & 3, kc = idx >> 11;
        int k = kc * 32 + (ln >> 4) * 8 + e;
        int n = nt * 16 + (ln & 15);
        g_w1s[idx] = f2bf(W1[k * HID + n]);
    } else if (idx < 8192) {                                // W2 (n>=60 zero)
        int j = idx - 4096;
        int e = j & 7, ln = (j >> 3) & 63, nt = (j >> 9) & 3, kc = j >> 11;
        int k = kc * 32 + (ln >> 4) * 8 + e;
        int n = nt * 16 + (ln & 15);
        g_w2s[j] = f2bf(n < NPATH ? W2[k * NPATH + n] : 0.0f);
    } else if (idx < 8192 + 75264) {                        // cg: source-order walk ->
        int j = idx - 8192;                                 // coalesced cg reads
        int k = j / 336;                                    // 224 k-slots (7kc x 32)
        int n = j % 336;                                    // 336 n-slots (21nt x 16)
        int kc = k >> 5, km = k & 31;
        int e  = km & 7, lh = km >> 3;
        int nt = n >> 4, lw = n & 15;
        int dst = ((kc * NTIL + nt) * 64 + (lh * 16 + lw)) * 8 + e;
        g_cgs[dst] = f2bf((k < KDIM && n < NIJ) ? cg[k * NIJ + n] : 0.0f);
    } else if (idx < 8192 + 75264 + 112) {                  // packed (p,y) per k-pair
        int j = idx - (8192 + 75264);
        int k0 = 2 * j, k1 = 2 * j + 1;
        unsigned p0 = 0, y0 = 0, p1 = 0, y1 = 0;
        if (k0 < KDIM) {
            for (int q = 0; q < NPATH; q++) if (rf[k0 * NPATH + q] != 0.0f) p0 = q;
            for (int q = 0; q < 9; q++)     if (ylm[k0 * 9 + q]   != 0.0f) y0 = q;
            for (int q = 0; q < NPATH; q++) if (rf[k1 * NPATH + q] != 0.0f) p1 = q;
            for (int q = 0; q < 9; q++)     if (ylm[k1 * 9 + q]   != 0.0f) y1 = q;
        }
        g_pyk[j] = p0 | (y0 << 8) | (p1 << 16) | (y1 << 24);
    }
}

// Per-wave LDS slice -- wave-private, reused across the two 16-row z-sets.
// Hw stride 88 u16 = 176 B: (l16, l16+8) rows pair banks = exact 2-way (free).
struct __align__(16) WaveMem {
    unsigned short Hw[16][88];   // 2816 B  hidden activations (B -> C)
    unsigned short Rw[16][61];   // 1952 B  radial path weights (C -> D)
    float          Yw[16][9];    //  576 B  spherical harmonics (A -> D)
};                               // 5344 B per wave; x4 = 21376 B

union frag { bf16x8 v; unsigned int d[4]; };

// Plain __launch_bounds__(256): round 2 proved forcing low VGPR spills the
// accumulators (+80 MB scratch traffic).
__global__ __launch_bounds__(256) void fused_kernel(
    const float* __restrict__ r, const float* __restrict__ b1,
    const float* __restrict__ b2, float* __restrict__ out)
{
    __shared__ WaveMem wm[4];

    const int tid  = threadIdx.x;
    const int wv   = tid >> 6;
    const int lane = tid & 63;
    const int quad = lane >> 4;
    const int l16  = lane & 15;
    const int z0   = blockIdx.x * 128;     // 32 z-rows per wave, 4 waves
    WaveMem& W = wm[wv];

    frag az0[7], az1[7];

    // Phases A-D for one 16-row z-set, writing az fragments for z = l16.
    // Macro (not runtime loop) so every az index is compile-time (rule #20).
#define PHASES_AD(AZ, ZBASE)                                                          \
    {                                                                                 \
        const int zg = (ZBASE) + l16;                                                 \
        float x = r[zg * 3 + 0], y = r[zg * 3 + 1], zc = r[zg * 3 + 2];               \
        float rad = sqrtf(x * x + y * y + zc * zc);                                   \
        if (quad == 0) {                                                              \
            float inv = 1.0f / (rad + 1e-12f);                                        \
            float nx = x * inv, ny = y * inv, nz = zc * inv;                          \
            const float c0 = 0.28209479177387814f, c1 = 0.4886025119029199f;          \
            const float c2a = 1.0925484305920792f, c2b = 0.31539156525252005f,        \
                        c2c = 0.5462742152960396f;                                    \
            W.Yw[l16][0] = c0;                                                        \
            W.Yw[l16][1] = c1 * ny;                                                   \
            W.Yw[l16][2] = c1 * nz;                                                   \
            W.Yw[l16][3] = c1 * nx;                                                   \
            W.Yw[l16][4] = c2a * nx * ny;                                             \
            W.Yw[l16][5] = c2a * ny * nz;                                             \
            W.Yw[l16][6] = c2b * (3.0f * nz * nz - 1.0f);                             \
            W.Yw[l16][7] = c2a * nx * nz;                                             \
            W.Yw[l16][8] = c2c * (nx * nx - ny * ny);                                 \
        }                                                                             \
        frag A0, A1;                                                                  \
        {                                                                             \
            const float step = 3.5f / 63.0f;                                          \
            const float NL2E = -5.770780163555852f;   /* -4 * log2(e) */              \
            _Pragma("unroll")                                                         \
            for (int ii = 0; ii < 4; ii++) {                                          \
                int i0 = quad * 8 + 2 * ii;                                           \
                float d0 = rad - (float)i0 * step;                                    \
                float d1 = rad - (float)(i0 + 1) * step;                              \
                A0.d[ii] = (unsigned)f2bf(__builtin_amdgcn_exp2f(d0 * d0 * NL2E))     \
                         | ((unsigned)f2bf(__builtin_amdgcn_exp2f(d1 * d1 * NL2E)) << 16); \
                int i2 = 32 + i0;                                                     \
                float e0 = rad - (float)i2 * step;                                    \
                float e1 = rad - (float)(i2 + 1) * step;                              \
                A1.d[ii] = (unsigned)f2bf(__builtin_amdgcn_exp2f(e0 * e0 * NL2E))     \
                         | ((unsigned)f2bf(__builtin_amdgcn_exp2f(e1 * e1 * NL2E)) << 16); \
            }                                                                         \
        }                                                                             \
        _Pragma("unroll")                                                             \
        for (int nt = 0; nt < 4; nt++) {                                              \
            bf16x8 bb0 = *(const bf16x8*)&g_w1s[((0 * 4 + nt) * 64 + lane) * 8];      \
            bf16x8 bb1 = *(const bf16x8*)&g_w1s[((1 * 4 + nt) * 64 + lane) * 8];      \
            f32x4 acc = {0.f, 0.f, 0.f, 0.f};                                         \
            acc = __builtin_amdgcn_mfma_f32_16x16x32_bf16(A0.v, bb0, acc, 0, 0, 0);   \
            acc = __builtin_amdgcn_mfma_f32_16x16x32_bf16(A1.v, bb1, acc, 0, 0, 0);   \
            int h = nt * 16 + l16;                                                    \
            float bias = b1[h];                                                       \
            _Pragma("unroll")                                                         \
            for (int rr = 0; rr < 4; rr++) {                                          \
                float v = acc[rr] + bias;                                             \
                v = v > 0.0f ? v : 0.0f;                                              \
                W.Hw[quad * 4 + rr][h] = f2bf(v);                                     \
            }                                                                         \
        }                                                                             \
        asm volatile("s_waitcnt lgkmcnt(0)" ::: "memory");                            \
        __builtin_amdgcn_sched_barrier(0);                                            \
        {                                                                             \
            bf16x8 h0 = *(const bf16x8*)&W.Hw[l16][0 + quad * 8];                     \
            bf16x8 h1 = *(const bf16x8*)&W.Hw[l16][32 + quad * 8];                    \
            _Pragma("unroll")                                                         \
            for (int nt = 0; nt < 4; nt++) {                                          \
                bf16x8 bb0 = *(const bf16x8*)&g_w2s[((0 * 4 + nt) * 64 + lane) * 8];  \
                bf16x8 bb1 = *(const bf16x8*)&g_w2s[((1 * 4 + nt) * 64 + lane) * 8];  \
                f32x4 acc = {0.f, 0.f, 0.f, 0.f};                                     \
                acc = __builtin_amdgcn_mfma_f32_16x16x32_bf16(h0, bb0, acc, 0, 0, 0); \
                acc = __builtin_amdgcn_mfma_f32_16x16x32_bf16(h1, bb1, acc, 0, 0, 0); \
                int p = nt * 16 + l16;                                                \
                if (p < NPATH) {                                                      \
                    float bias = b2[p];                                               \
                    _Pragma("unroll")                                                 \
                    for (int rr = 0; rr < 4; rr++)                                    \
                        W.Rw[quad * 4 + rr][p] = f2bf(acc[rr] + bias);                \
                }                                                                     \
            }                                                                         \
        }                                                                             \
        asm volatile("s_waitcnt lgkmcnt(0)" ::: "memory");                            \
        __builtin_amdgcn_sched_barrier(0);                                            \
        _Pragma("unroll")                                                             \
        for (int kc = 0; kc < 7; kc++) {                                              \
            _Pragma("unroll")                                                         \
            for (int ii = 0; ii < 4; ii++) {                                          \
                unsigned py = g_pyk[kc * 16 + quad * 4 + ii];                         \
                float cA = bf2f(W.Rw[l16][py & 255])         * W.Yw[l16][(py >> 8) & 255]; \
                float cB = bf2f(W.Rw[l16][(py >> 16) & 255]) * W.Yw[l16][py >> 24];   \
                AZ[kc].d[ii] = (unsigned)f2bf(cA) | ((unsigned)f2bf(cB) << 16);       \
            }                                                                         \
        }                                                                             \
        asm volatile("s_waitcnt lgkmcnt(0)" ::: "memory");                            \
        __builtin_amdgcn_sched_barrier(0);                                            \
    }

    PHASES_AD(az0, z0 + wv * 32)          // z-set 0: rows [wv*32, +16)
    PHASES_AD(az1, z0 + wv * 32 + 16)     // z-set 1: rows [wv*32+16, +16) (LDS reused)
#undef PHASES_AD

    // ---- Phase E: each bg fragment feeds TWO MFMAs (halves g_cgs traffic) ----
    // out row = z0 + wv*32 + set*16 + quad*4 + rr, col = nt*16 + l16.
    const int obase = (z0 + wv * 32 + quad * 4) * NIJ + l16;
    #pragma unroll 3
    for (int nt = 0; nt < NTIL; nt++) {
        f32x4 accA = {0.f, 0.f, 0.f, 0.f};
        f32x4 accB = {0.f, 0.f, 0.f, 0.f};
        #pragma unroll
        for (int kc = 0; kc < 7; kc++) {
            bf16x8 bg = *(const bf16x8*)&g_cgs[((kc * NTIL + nt) * 64 + lane) * 8];
            accA = __builtin_amdgcn_mfma_f32_16x16x32_bf16(az0[kc].v, bg, accA, 0, 0, 0);
            accB = __builtin_amdgcn_mfma_f32_16x16x32_bf16(az1[kc].v, bg, accB, 0, 0, 0);
        }
        int col = nt * 16 + l16;
        if (col < NIJ) {                     // last tile covers cols 320..335
            #pragma unroll
            for (int rr = 0; rr < 4; rr++) {
                out[obase + rr * NIJ + nt * 16]              = accA[rr];
                out[obase + (16 + rr) * NIJ + nt * 16]       = accB[rr];
            }
        }
    }
}

extern "C" void kernel_launch(void* const* d_in, const int* in_sizes, int n_in,
                              void* d_out, int out_size, void* d_ws, size_t ws_size,
                              hipStream_t stream) {
    const float* r   = (const float*)d_in[0];
    const float* W1  = (const float*)d_in[1];
    const float* b1  = (const float*)d_in[2];
    const float* W2  = (const float*)d_in[3];
    const float* b2  = (const float*)d_in[4];
    const float* cg  = (const float*)d_in[5];
    const float* rf  = (const float*)d_in[6];
    const float* ylm = (const float*)d_in[7];
    float* out = (float*)d_out;

    const int Z = in_sizes[0] / 3;

    prep_kernel<<<327, 256, 0, stream>>>(W1, W2, cg, rf, ylm);
    fused_kernel<<<Z / 128, 256, 0, stream>>>(r, b1, b2, out);
}